// Round 2
// baseline (133.146 us; speedup 1.0000x reference)
//
#include <hip/hip_runtime.h>

#define H 256
#define NB 2048
#define BATCH 8
#define NSPLIT 8
#define KSPAN (NB / NSPLIT)   // 256 keys per split
#define NITER (KSPAN / 64)    // 4 double-buffered 64-key tiles

typedef unsigned short u16;
using bf16x8 = __attribute__((ext_vector_type(8))) __bf16;
using f32x4  = __attribute__((ext_vector_type(4))) float;

typedef const __attribute__((address_space(1))) void gv_t;
typedef __attribute__((address_space(3))) void lv_t;

// async 16B-per-lane global->LDS: lds dst is wave-uniform base, lane i lands at base+16*i
__device__ __forceinline__ void gl_lds16(const void* g, void* l) {
    __builtin_amdgcn_global_load_lds((gv_t*)g, (lv_t*)l, 16, 0, 0);
}

#define MFMA(a, b, c) __builtin_amdgcn_mfma_f32_16x16x32_bf16(a, b, c, 0, 0, 0)

__device__ __forceinline__ u16 f2bf(float f) {
    union { float f; unsigned u; } v; v.f = f;
    unsigned r = v.u + 0x7fffu + ((v.u >> 16) & 1u);  // RNE
    return (u16)(r >> 16);
}

__device__ __forceinline__ bf16x8 cvt8(const float* p) {
    float4 f0 = *(const float4*)p;
    float4 f1 = *(const float4*)(p + 4);
    union { bf16x8 v; u16 u[8]; } r;
    r.u[0] = f2bf(f0.x); r.u[1] = f2bf(f0.y); r.u[2] = f2bf(f0.z); r.u[3] = f2bf(f0.w);
    r.u[4] = f2bf(f1.x); r.u[5] = f2bf(f1.y); r.u[6] = f2bf(f1.z); r.u[7] = f2bf(f1.w);
    return r.v;
}

// ---- K1 prep (fused wprep + aT-gemm, one stage):
//   blocks 0..255:  wvw[f] = Wv[f,:]·Ww, kbv[f] = Wk[f,:]·bq, block 0 also cc = bv·Ww
//   blocks 256..263: aT[f][e] = bf16((Wk_bf[f,:]·Wq_bf[e,:])/16) — weights converted
//   to bf16 IN-KERNEL (no wqb/wkb roundtrip, no extra launch). ----
__global__ __launch_bounds__(256) void prep_kernel(
        const float* __restrict__ Wq, const float* __restrict__ Wk,
        const float* __restrict__ Wv, const float* __restrict__ Ww,
        const float* __restrict__ bq, const float* __restrict__ bv,
        u16* __restrict__ aTb, float* __restrict__ wvw,
        float* __restrict__ kbv, float* __restrict__ ccp) {
    __shared__ u16 bt[16384];   // 32KB fragment-major (gemm blocks only)
    int id = blockIdx.x, t = threadIdx.x;

    if (id < 256) {   // reduction blocks
        int f = id;
        float p = Wv[f * H + t] * Ww[t];
        float r = Wk[f * H + t] * bq[t];
        float c = (id == 0) ? bv[t] * Ww[t] : 0.f;
        for (int o = 32; o; o >>= 1) {
            p += __shfl_xor(p, o); r += __shfl_xor(r, o); c += __shfl_xor(c, o);
        }
        __shared__ float redp[4], redr[4], redc[4];
        int w = t >> 6, lane = t & 63;
        if (lane == 0) { redp[w] = p; redr[w] = r; redc[w] = c; }
        __syncthreads();
        if (t == 0) {
            wvw[f] = redp[0] + redp[1] + redp[2] + redp[3];
            kbv[f] = redr[0] + redr[1] + redr[2] + redr[3];
            if (f == 0) ccp[0] = redc[0] + redc[1] + redc[2] + redc[3];
        }
        return;
    }

    // gemm blocks: gid 0..7 -> 128x64 tile of aT (256x256), K=256
    int gid = id - 256;
    int mb = (gid >> 2) * 128, nb = (gid & 3) * 64;
    int w = t >> 6, lane = t & 63, l15 = lane & 15, quad = lane >> 4;

    {   // stage B = bf16(Wq rows nb..nb+63), fragment-major (same layout as gl_lds16)
        const float* src = Wq + (nb + w * 16 + l15) * H + quad * 8;
        #pragma unroll
        for (int ks = 0; ks < 8; ++ks)
            *(bf16x8*)(bt + (w * 8 + ks) * 512 + lane * 8) = cvt8(src + ks * 32);
    }

    bf16x8 a[2][8];
    #pragma unroll
    for (int mi = 0; mi < 2; ++mi) {
        const float* ab = Wk + (mb + w * 32 + mi * 16 + l15) * H + quad * 8;
        #pragma unroll
        for (int ks = 0; ks < 8; ++ks) a[mi][ks] = cvt8(ab + ks * 32);
    }
    __syncthreads();

    f32x4 acc[2][4] = {};
    #pragma unroll
    for (int ks = 0; ks < 8; ++ks)
        #pragma unroll
        for (int tt = 0; tt < 4; ++tt) {
            bf16x8 b = *(const bf16x8*)(bt + ((tt * 8 + ks) * 64 + lane) * 8);
            acc[0][tt] = MFMA(a[0][ks], b, acc[0][tt]);
            acc[1][tt] = MFMA(a[1][ks], b, acc[1][tt]);
        }

    #pragma unroll
    for (int mi = 0; mi < 2; ++mi) {
        int m = mb + w * 32 + mi * 16 + quad * 4;
        #pragma unroll
        for (int tt = 0; tt < 4; ++tt) {
            int n = nb + tt * 16 + l15;
            #pragma unroll
            for (int r2 = 0; r2 < 4; ++r2)
                aTb[(m + r2) * H + n] = f2bf(acc[mi][tt][r2] * 0.0625f);
        }
    }
}

// ---- K2 xt (fused cvtu + T-gemm): block = 128 rows x 64 cols of T.
//   Converts its x rows f32->bf16 in registers (identical f2bf bits to old cvtu);
//   nb==0 block of each row-group writes xbf + uee once. Swizzle puts the 4
//   blocks sharing a row-slice on the SAME XCD so redundant x reads are L2 hits. ----
__global__ __launch_bounds__(256) void xt_kernel(
        const float* __restrict__ x, const u16* __restrict__ aTb,
        const float* __restrict__ wvw, const float* __restrict__ kbv,
        const float* __restrict__ ccp,
        u16* __restrict__ xbf, float2* __restrict__ uee, u16* __restrict__ Tbf) {
    __shared__ u16 bt[16384];   // 32KB fragment-major B = aT slice
    int id = blockIdx.x, tid = threadIdx.x;
    int nbI = (id >> 3) & 3;               // same-XCD grouping: sharers are ids {k,k+8,k+16,k+24}
    int mb4 = (id & 7) + (id >> 5) * 8;    // 0..127, bijective
    int mb = mb4 * 128, nb = nbI * 64;
    int w = tid >> 6, lane = tid & 63, l15 = lane & 15, quad = lane >> 4;

    {   // stage B = aT rows nb..nb+63 (bf16 global, written by K1)
        const u16* gsrc = aTb + (nb + w * 16 + l15) * H + quad * 8;
        #pragma unroll
        for (int ks = 0; ks < 8; ++ks)
            gl_lds16(gsrc + ks * 32, bt + (w * 8 + ks) * 512);
    }

    // A: convert x rows to bf16 fragments; accumulate uee dots from the f32 values
    bf16x8 a[2][8];
    float s[2] = {0.f, 0.f}, d[2] = {0.f, 0.f};
    #pragma unroll
    for (int ks = 0; ks < 8; ++ks) {
        const float* wp = wvw + ks * 32 + quad * 8;
        const float* kp = kbv + ks * 32 + quad * 8;
        float4 w0 = *(const float4*)wp, w1 = *(const float4*)(wp + 4);
        float4 k0 = *(const float4*)kp, k1 = *(const float4*)(kp + 4);
        #pragma unroll
        for (int mi = 0; mi < 2; ++mi) {
            const float* xr = x + (size_t)(mb + w * 32 + mi * 16 + l15) * H + ks * 32 + quad * 8;
            float4 f0 = *(const float4*)xr;
            float4 f1 = *(const float4*)(xr + 4);
            union { bf16x8 v; u16 u[8]; } r;
            r.u[0] = f2bf(f0.x); r.u[1] = f2bf(f0.y); r.u[2] = f2bf(f0.z); r.u[3] = f2bf(f0.w);
            r.u[4] = f2bf(f1.x); r.u[5] = f2bf(f1.y); r.u[6] = f2bf(f1.z); r.u[7] = f2bf(f1.w);
            a[mi][ks] = r.v;
            s[mi] += f0.x * w0.x + f0.y * w0.y + f0.z * w0.z + f0.w * w0.w
                   + f1.x * w1.x + f1.y * w1.y + f1.z * w1.z + f1.w * w1.w;
            d[mi] += f0.x * k0.x + f0.y * k0.y + f0.z * k0.z + f0.w * k0.w
                   + f1.x * k1.x + f1.y * k1.y + f1.z * k1.z + f1.w * k1.w;
        }
    }

    if (nbI == 0) {   // this block owns the xbf + uee writes for its 128 rows
        #pragma unroll
        for (int mi = 0; mi < 2; ++mi) {
            u16* xo = xbf + (size_t)(mb + w * 32 + mi * 16 + l15) * H + quad * 8;
            #pragma unroll
            for (int ks = 0; ks < 8; ++ks)
                *(bf16x8*)(xo + ks * 32) = a[mi][ks];
        }
        float cc = ccp[0];
        #pragma unroll
        for (int mi = 0; mi < 2; ++mi) {
            float ss = s[mi] + __shfl_xor(s[mi], 16);
            ss += __shfl_xor(ss, 32);
            float dd = d[mi] + __shfl_xor(d[mi], 16);
            dd += __shfl_xor(dd, 32);
            if (quad == 0) {
                int row = mb + w * 32 + mi * 16 + l15;
                float e = __expf(dd * 0.0625f);
                uee[row] = make_float2(e * (ss + cc), e);
            }
        }
    }
    __syncthreads();

    f32x4 acc[2][4] = {};
    #pragma unroll
    for (int ks = 0; ks < 8; ++ks)
        #pragma unroll
        for (int tt = 0; tt < 4; ++tt) {
            bf16x8 b = *(const bf16x8*)(bt + ((tt * 8 + ks) * 64 + lane) * 8);
            acc[0][tt] = MFMA(a[0][ks], b, acc[0][tt]);
            acc[1][tt] = MFMA(a[1][ks], b, acc[1][tt]);
        }

    #pragma unroll
    for (int mi = 0; mi < 2; ++mi) {
        int m = mb + w * 32 + mi * 16 + quad * 4;
        #pragma unroll
        for (int tt = 0; tt < 4; ++tt) {
            int n = nb + tt * 16 + l15;
            #pragma unroll
            for (int r2 = 0; r2 < 4; ++r2)
                Tbf[(size_t)(m + r2) * H + n] = f2bf(acc[mi][tt][r2]);
        }
    }
}

// ---- attention: logit(n,m) = T[n]·x[m]; num += e^logit·(e·u)_m, den += e^logit·e_m.
//      64-key double-buffered tiles, t-outer/ks-inner so each 16-key group's exp
//      burst overlaps the next group's MFMA burst. setprio(1) around the MFMA
//      cluster (T5: waves hit exp/MFMA phases at different times).
//      Grid 512 = 2 blocks/CU resident; b in low 3 bits pins batch b -> XCD b. ----
__global__ __launch_bounds__(256, 2) void attn_kernel(
        const u16* __restrict__ T, const u16* __restrict__ xbf,
        const float2* __restrict__ uee,
        float* __restrict__ pnum, float* __restrict__ pden) {
    __shared__ u16 kt[32768];   // 2 x 32KB fragment-major 64-key tiles
    int tid = threadIdx.x;
    int id = blockIdx.x;
    int b = id & 7, rest = id >> 3;
    int qc = rest & 7, sp = rest >> 3;
    int w = tid >> 6, lane = tid & 63, l15 = lane & 15, quad = lane >> 4;
    int qb = qc * 256;

    // resident A fragments: 64 q-rows per wave (4 x 16)
    bf16x8 aq[4][8];
    {
        const u16* qbase = T + (size_t)(b * NB + qb + w * 64 + l15) * H + quad * 8;
        #pragma unroll
        for (int mi = 0; mi < 4; ++mi)
            #pragma unroll
            for (int ks = 0; ks < 8; ++ks)
                aq[mi][ks] = *(const bf16x8*)(qbase + mi * 16 * H + ks * 32);
    }

    const u16* xb = xbf + (size_t)b * NB * H;
    const float2* uep = uee + (size_t)b * NB;
    const int kb0 = sp * KSPAN;

    // wave w stages t-group w (16 keys, 8 ks-chunks of 1KB) of each 64-key tile
    const u16* gsrc = xb + (size_t)(kb0 + w * 16 + l15) * H + quad * 8;
    #pragma unroll
    for (int j = 0; j < 8; ++j)
        gl_lds16(gsrc + j * 32, kt + (w * 8 + j) * 512);
    __syncthreads();

    float ls[4][4] = {}, as_[4][4] = {};

    #pragma unroll 1
    for (int h = 0; h < NITER; ++h) {
        const u16* ktc = kt + (h & 1) * 16384;
        if (h + 1 < NITER) {   // stage next 64-key tile into the other buffer
            u16* dst = kt + ((h & 1) ^ 1) * 16384;
            const u16* g2 = gsrc + (size_t)(h + 1) * 64 * H;
            #pragma unroll
            for (int j = 0; j < 8; ++j)
                gl_lds16(g2 + j * 32, dst + (w * 8 + j) * 512);
        }
        int kb64 = kb0 + h * 64;
        float2 uv[4];
        #pragma unroll
        for (int t = 0; t < 4; ++t) uv[t] = uep[kb64 + t * 16 + l15];

        #pragma unroll
        for (int t = 0; t < 4; ++t) {
            f32x4 acc[4] = {};
            __builtin_amdgcn_s_setprio(1);
            #pragma unroll
            for (int ks = 0; ks < 8; ++ks) {
                bf16x8 bfr = *(const bf16x8*)(ktc + ((t * 8 + ks) * 64 + lane) * 8);
                acc[0] = MFMA(aq[0][ks], bfr, acc[0]);
                acc[1] = MFMA(aq[1][ks], bfr, acc[1]);
                acc[2] = MFMA(aq[2][ks], bfr, acc[2]);
                acc[3] = MFMA(aq[3][ks], bfr, acc[3]);
            }
            __builtin_amdgcn_s_setprio(0);
            #pragma unroll
            for (int mi = 0; mi < 4; ++mi)
                #pragma unroll
                for (int r = 0; r < 4; ++r) {
                    float p = __expf(acc[mi][r]);
                    as_[mi][r] += p * uv[t].x;
                    ls[mi][r]  += p * uv[t].y;
                }
        }
        __syncthreads();
    }

    // reduce over the 16 key-columns (l15)
    #pragma unroll
    for (int mi = 0; mi < 4; ++mi)
        #pragma unroll
        for (int r = 0; r < 4; ++r)
            for (int o = 1; o < 16; o <<= 1) {
                ls[mi][r]  += __shfl_xor(ls[mi][r], o);
                as_[mi][r] += __shfl_xor(as_[mi][r], o);
            }

    if (l15 == 0) {
        size_t base = (size_t)(sp * BATCH + b) * NB + qb + w * 64 + quad * 4;
        #pragma unroll
        for (int mi = 0; mi < 4; ++mi)
            #pragma unroll
            for (int r = 0; r < 4; ++r) {
                pnum[base + mi * 16 + r] = as_[mi][r];
                pden[base + mi * 16 + r] = ls[mi][r];
            }
    }
}

// ---- combine K-splits: out = sum(num)/sum(den) + bw ----
__global__ __launch_bounds__(256) void finalize_kernel(
        const float* __restrict__ pnum, const float* __restrict__ pden,
        const float* __restrict__ bw, float* __restrict__ out) {
    int i = blockIdx.x * 256 + threadIdx.x;   // i = b*NB + n
    float num = 0.f, den = 0.f;
    for (int sp = 0; sp < NSPLIT; ++sp) {
        num += pnum[sp * (BATCH * NB) + i];
        den += pden[sp * (BATCH * NB) + i];
    }
    out[i] = num / den + bw[0];
}

extern "C" void kernel_launch(void* const* d_in, const int* in_sizes, int n_in,
                              void* d_out, int out_size, void* d_ws, size_t ws_size,
                              hipStream_t stream) {
    (void)in_sizes; (void)n_in; (void)out_size; (void)ws_size;
    const float* x  = (const float*)d_in[0];
    const float* Wq = (const float*)d_in[1];
    const float* bq = (const float*)d_in[2];
    const float* Wk = (const float*)d_in[3];
    const float* bk = (const float*)d_in[4];  (void)bk;  // cancels in softmax
    const float* Wv = (const float*)d_in[5];
    const float* bv = (const float*)d_in[6];
    const float* Ww = (const float*)d_in[7];
    const float* bw = (const float*)d_in[8];
    float* out = (float*)d_out;

    u16* xbf = (u16*)d_ws;                     // 4194304 u16 (8 MB)
    u16* Tbf = xbf + 4194304;                  // 4194304 u16 (8 MB)
    u16* aTb = Tbf + 4194304;                  // 65536 u16
    float* wvw = (float*)(aTb + 65536);        // 256 f32
    float* kbv = wvw + 256;                    // 256 f32
    float* ccp = kbv + 256;                    // 4 f32 (1 used, keeps 8B align)
    float2* uee = (float2*)(ccp + 4);          // 16384 float2
    float* pnum = (float*)(uee + 16384);       // NSPLIT*16384 f32
    float* pden = pnum + NSPLIT * BATCH * NB;  // NSPLIT*16384 f32

    hipLaunchKernelGGL(prep_kernel, dim3(264), dim3(256), 0, stream,
                       Wq, Wk, Wv, Ww, bq, bv, aTb, wvw, kbv, ccp);
    hipLaunchKernelGGL(xt_kernel, dim3(512), dim3(256), 0, stream,
                       x, aTb, wvw, kbv, ccp, xbf, uee, Tbf);
    hipLaunchKernelGGL(attn_kernel, dim3(8 * 8 * NSPLIT), dim3(256), 0, stream,
                       Tbf, xbf, uee, pnum, pden);
    hipLaunchKernelGGL(finalize_kernel, dim3(64), dim3(256), 0, stream,
                       pnum, pden, bw, out);
}